// Round 1
// baseline (574.320 us; speedup 1.0000x reference)
//
#include <hip/hip_runtime.h>
#include <math.h>

// DrugEncoder: 2x TransformerConv (heads=1) + global mean pool.
// N=50000 nodes, E=800000 edges, G=512 graphs, D_IN=64, D_HID=D_EMB=128.
//
// Plan:
//  1) CSR-by-dst build (hist -> scan -> fill). Reused by both conv layers.
//  2) tiled_linear<DIN>: fused 4-way linear (q,k,v,skip) fp32 register-tiled GEMM.
//  3) edge_agg: one wave per dst node, online-softmax aggregation, no atomics.
//  4) pool: batch sorted -> binary search range + mean.

constexpr int D1 = 64;
constexpr int DH = 128;
constexpr int SCHUNK = 1024;

// ---------------- CSR build ----------------

__global__ void hist_kernel(const int* __restrict__ dst, int* __restrict__ deg, int E) {
  int e = blockIdx.x * blockDim.x + threadIdx.x;
  if (e < E) atomicAdd(&deg[dst[e]], 1);
}

__global__ void scan_chunks(const int* __restrict__ deg, int* __restrict__ incl,
                            int* __restrict__ sums, int N) {
  __shared__ int lds[256];
  int b = blockIdx.x, tid = threadIdx.x;
  int base = b * SCHUNK + tid * 4;
  int e0 = (base + 0 < N) ? deg[base + 0] : 0;
  int e1 = (base + 1 < N) ? deg[base + 1] : 0;
  int e2 = (base + 2 < N) ? deg[base + 2] : 0;
  int e3 = (base + 3 < N) ? deg[base + 3] : 0;
  int t0 = e0, t1 = t0 + e1, t2 = t1 + e2, t3 = t2 + e3;
  lds[tid] = t3;
  __syncthreads();
  for (int off = 1; off < 256; off <<= 1) {
    int v = (tid >= off) ? lds[tid - off] : 0;
    __syncthreads();
    lds[tid] += v;
    __syncthreads();
  }
  int excl = (tid > 0) ? lds[tid - 1] : 0;
  if (base + 0 < N) incl[base + 0] = t0 + excl;
  if (base + 1 < N) incl[base + 1] = t1 + excl;
  if (base + 2 < N) incl[base + 2] = t2 + excl;
  if (base + 3 < N) incl[base + 3] = t3 + excl;
  if (tid == 255) sums[b] = lds[255];
}

__global__ void scan_top(const int* __restrict__ sums, int* __restrict__ offs, int nch) {
  if (threadIdx.x == 0 && blockIdx.x == 0) {
    int run = 0;
    for (int i = 0; i < nch; ++i) { offs[i] = run; run += sums[i]; }
  }
}

__global__ void finalize_rowptr(const int* __restrict__ incl, const int* __restrict__ offs,
                                int* __restrict__ rowptr, int N) {
  int n = blockIdx.x * blockDim.x + threadIdx.x;
  if (n < N) rowptr[n + 1] = incl[n] + offs[n / SCHUNK];
  if (n == 0) rowptr[0] = 0;
}

__global__ void fill_csr(const int* __restrict__ src, const int* __restrict__ dst,
                         const int* __restrict__ rowptr, int* __restrict__ fill,
                         int* __restrict__ csr_src, int E) {
  int e = blockIdx.x * blockDim.x + threadIdx.x;
  if (e < E) {
    int d = dst[e];
    int pos = rowptr[d] + atomicAdd(&fill[d], 1);
    csr_src[pos] = src[e];
  }
}

// ---------------- fused 4-way linear (fp32) ----------------
// out[y][n][j] = b_y[j] + sum_i x[n][i] * W_y[i][j],  y selected by blockIdx.y.
// Block: 256 threads, 64-node x 128-col tile; per-thread 8 nodes x 4 cols.

template <int DIN>
__global__ __launch_bounds__(256) void tiled_linear(
    const float* __restrict__ x, int N,
    const float* __restrict__ W0, const float* __restrict__ B0, float* __restrict__ O0,
    const float* __restrict__ W1, const float* __restrict__ B1, float* __restrict__ O1,
    const float* __restrict__ W2, const float* __restrict__ B2, float* __restrict__ O2,
    const float* __restrict__ W3, const float* __restrict__ B3, float* __restrict__ O3) {
  constexpr int NT = 64;
  constexpr int LDX = NT + 4;  // keep float4 alignment of rows; pad vs bank conflicts
  __shared__ float xs[DIN * LDX];
  const float* W; const float* B; float* O;
  switch (blockIdx.y) {
    case 0: W = W0; B = B0; O = O0; break;
    case 1: W = W1; B = B1; O = O1; break;
    case 2: W = W2; B = B2; O = O2; break;
    default: W = W3; B = B3; O = O3; break;
  }
  int tid = threadIdx.x;
  int n0 = blockIdx.x * NT;
  // load x tile transposed: xs[i][nl] = x[n0+nl][i]
  for (int idx = tid; idx < DIN * NT; idx += 256) {
    int nl = idx / DIN;
    int i = idx - nl * DIN;
    int n = n0 + nl;
    xs[i * LDX + nl] = (n < N) ? x[(size_t)n * DIN + i] : 0.f;
  }
  __syncthreads();

  int tc = tid & 31;   // col group: cols 4*tc .. 4*tc+3
  int tn = tid >> 5;   // node group: nodes 8*tn .. 8*tn+7
  float acc[8][4];
#pragma unroll
  for (int a = 0; a < 8; ++a)
#pragma unroll
    for (int c = 0; c < 4; ++c) acc[a][c] = 0.f;

  const float4* Wp = (const float4*)W + tc;  // row i at Wp[i*32]
  for (int i = 0; i < DIN; ++i) {
    float4 w4 = Wp[(size_t)i * 32];
    float4 xa = *(const float4*)&xs[i * LDX + 8 * tn];
    float4 xb = *(const float4*)&xs[i * LDX + 8 * tn + 4];
    float xv[8] = {xa.x, xa.y, xa.z, xa.w, xb.x, xb.y, xb.z, xb.w};
#pragma unroll
    for (int a = 0; a < 8; ++a) {
      acc[a][0] += xv[a] * w4.x;
      acc[a][1] += xv[a] * w4.y;
      acc[a][2] += xv[a] * w4.z;
      acc[a][3] += xv[a] * w4.w;
    }
  }
  float4 b4 = *(const float4*)&B[4 * tc];
#pragma unroll
  for (int a = 0; a < 8; ++a) {
    int n = n0 + 8 * tn + a;
    if (n < N) {
      float4 o;
      o.x = acc[a][0] + b4.x;
      o.y = acc[a][1] + b4.y;
      o.z = acc[a][2] + b4.z;
      o.w = acc[a][3] + b4.w;
      *(float4*)&O[(size_t)n * 128 + 4 * tc] = o;
    }
  }
}

// ---------------- edge aggregation: one wave per dst node ----------------
// out[n] += softmax_over_edges(q[n].k[src]/sqrt(128)) . v[src]; optional ReLU.

template <bool RELU>
__global__ __launch_bounds__(256) void edge_agg(
    const float2* __restrict__ q, const float2* __restrict__ k, const float2* __restrict__ v,
    const int* __restrict__ rowptr, const int* __restrict__ csr_src,
    float* __restrict__ out, int N) {
  int lane = threadIdx.x;  // 64
  int wv = threadIdx.y;    // 4 waves/block
  int n = blockIdx.x * 4 + wv;
  if (n >= N) return;
  float2 q2 = q[(size_t)n * 64 + lane];
  int beg = rowptr[n], end = rowptr[n + 1];
  float m = -INFINITY, l = 0.f;
  float ax = 0.f, ay = 0.f;
  const float scale = 0.08838834764831845f;  // 1/sqrt(128)
  if (beg < end) {
    int s = csr_src[beg];
    float2 k2 = k[(size_t)s * 64 + lane];
    float2 v2 = v[(size_t)s * 64 + lane];
    for (int p = beg; p < end; ++p) {
      float2 kc = k2, vc = v2;
      if (p + 1 < end) {  // software pipeline next edge's rows
        int s2 = csr_src[p + 1];
        k2 = k[(size_t)s2 * 64 + lane];
        v2 = v[(size_t)s2 * 64 + lane];
      }
      float d = q2.x * kc.x + q2.y * kc.y;
#pragma unroll
      for (int off = 1; off < 64; off <<= 1) d += __shfl_xor(d, off);
      float sc = d * scale;
      float mn = fmaxf(m, sc);
      float cf = __expf(m - mn);   // first iter: exp(-inf)=0
      float ef = __expf(sc - mn);
      l = l * cf + ef;
      ax = ax * cf + ef * vc.x;
      ay = ay * cf + ef * vc.y;
      m = mn;
    }
  }
  float rl = 1.f / (l + 1e-16f);
  float* op = out + (size_t)n * 128 + lane * 2;
  float ox = op[0] + ax * rl;
  float oy = op[1] + ay * rl;
  if (RELU) { ox = fmaxf(ox, 0.f); oy = fmaxf(oy, 0.f); }
  op[0] = ox;
  op[1] = oy;
}

// ---------------- global mean pool (batch sorted) ----------------

__global__ __launch_bounds__(128) void pool_kernel(const float* __restrict__ h,
                                                   const int* __restrict__ batch,
                                                   float* __restrict__ out, int N) {
  int g = blockIdx.x;
  int lo = 0, hi = N;
  while (lo < hi) { int mid = (lo + hi) >> 1; if (batch[mid] < g) lo = mid + 1; else hi = mid; }
  int s0 = lo;
  hi = N;
  while (lo < hi) { int mid = (lo + hi) >> 1; if (batch[mid] <= g) lo = mid + 1; else hi = mid; }
  int s1 = lo;
  int j = threadIdx.x;
  float acc = 0.f;
  for (int n = s0; n < s1; ++n) acc += h[(size_t)n * 128 + j];
  out[(size_t)g * 128 + j] = acc / fmaxf((float)(s1 - s0), 1.f);
}

// ---------------- launch ----------------

extern "C" void kernel_launch(void* const* d_in, const int* in_sizes, int n_in,
                              void* d_out, int out_size, void* d_ws, size_t ws_size,
                              hipStream_t stream) {
  const float* x = (const float*)d_in[0];
  const int* ei = (const int*)d_in[1];
  const int* batch = (const int*)d_in[2];
  const float* Wq1 = (const float*)d_in[3];
  const float* bq1 = (const float*)d_in[4];
  const float* Wk1 = (const float*)d_in[5];
  const float* bk1 = (const float*)d_in[6];
  const float* Wv1 = (const float*)d_in[7];
  const float* bv1 = (const float*)d_in[8];
  const float* Ws1 = (const float*)d_in[9];
  const float* bs1 = (const float*)d_in[10];
  const float* Wq2 = (const float*)d_in[11];
  const float* bq2 = (const float*)d_in[12];
  const float* Wk2 = (const float*)d_in[13];
  const float* bk2 = (const float*)d_in[14];
  const float* Wv2 = (const float*)d_in[15];
  const float* bv2 = (const float*)d_in[16];
  const float* Ws2 = (const float*)d_in[17];
  const float* bs2 = (const float*)d_in[18];

  int N = in_sizes[0] / D1;  // 50000
  int E = in_sizes[1] / 2;   // 800000
  int NG = out_size / DH;    // 512
  const int* src = ei;
  const int* dst = ei + E;

  char* ws = (char*)d_ws;
  float* q = (float*)ws;  ws += (size_t)N * DH * 4;
  float* kk = (float*)ws; ws += (size_t)N * DH * 4;
  float* vv = (float*)ws; ws += (size_t)N * DH * 4;
  float* h1 = (float*)ws; ws += (size_t)N * DH * 4;
  float* h2 = (float*)ws; ws += (size_t)N * DH * 4;
  int* rowptr = (int*)ws; ws += (size_t)(N + 1) * 4;
  ws += 252;  // align
  int* deg = (int*)ws;  ws += (size_t)N * 4;
  int* fill = (int*)ws; ws += (size_t)N * 4;
  int* incl = (int*)ws; ws += (size_t)N * 4;
  int* offs = (int*)ws; ws += 1024;
  int* sums = (int*)ws; ws += 1024;
  int* csr = (int*)ws;  ws += (size_t)E * 4;

  int nch = (N + SCHUNK - 1) / SCHUNK;

  hipMemsetAsync(deg, 0, (size_t)N * 4, stream);
  hipMemsetAsync(fill, 0, (size_t)N * 4, stream);

  hist_kernel<<<(E + 255) / 256, 256, 0, stream>>>(dst, deg, E);
  scan_chunks<<<nch, 256, 0, stream>>>(deg, incl, sums, N);
  scan_top<<<1, 64, 0, stream>>>(sums, offs, nch);
  finalize_rowptr<<<(N + 255) / 256, 256, 0, stream>>>(incl, offs, rowptr, N);
  fill_csr<<<(E + 255) / 256, 256, 0, stream>>>(src, dst, rowptr, fill, csr, E);

  dim3 gl((N + 63) / 64, 4);
  // layer 1: q,k,v + skip(out-init) from x
  tiled_linear<D1><<<gl, 256, 0, stream>>>(x, N, Wq1, bq1, q, Wk1, bk1, kk,
                                           Wv1, bv1, vv, Ws1, bs1, h1);
  edge_agg<true><<<(N + 3) / 4, dim3(64, 4), 0, stream>>>(
      (const float2*)q, (const float2*)kk, (const float2*)vv, rowptr, csr, h1, N);
  // layer 2 on h1
  tiled_linear<DH><<<gl, 256, 0, stream>>>(h1, N, Wq2, bq2, q, Wk2, bk2, kk,
                                           Wv2, bv2, vv, Ws2, bs2, h2);
  edge_agg<false><<<(N + 3) / 4, dim3(64, 4), 0, stream>>>(
      (const float2*)q, (const float2*)kk, (const float2*)vv, rowptr, csr, h2, N);
  // mean pool
  pool_kernel<<<NG, 128, 0, stream>>>(h2, batch, (float*)d_out, N);
}

// Round 3
// 431.370 us; speedup vs baseline: 1.3314x; 1.3314x over previous
//
#include <hip/hip_runtime.h>
#include <math.h>

// DrugEncoder: 2x TransformerConv (heads=1) + global mean pool.
// N=50000 nodes, E=800000 edges, G=512 graphs, D_IN=64, D_HID=D_EMB=128.
//
// R2: bf16 interleaved kv gather (half the bytes, one dwordx4/lane/edge),
//     2 online-softmax streams per wave + depth-2 prefetch.

constexpr int D1 = 64;
constexpr int DH = 128;
constexpr int SCHUNK = 1024;

// ---------------- CSR build ----------------

__global__ void hist_kernel(const int* __restrict__ dst, int* __restrict__ deg, int E) {
  int e = blockIdx.x * blockDim.x + threadIdx.x;
  if (e < E) atomicAdd(&deg[dst[e]], 1);
}

__global__ void scan_chunks(const int* __restrict__ deg, int* __restrict__ incl,
                            int* __restrict__ sums, int N) {
  __shared__ int lds[256];
  int b = blockIdx.x, tid = threadIdx.x;
  int base = b * SCHUNK + tid * 4;
  int e0 = (base + 0 < N) ? deg[base + 0] : 0;
  int e1 = (base + 1 < N) ? deg[base + 1] : 0;
  int e2 = (base + 2 < N) ? deg[base + 2] : 0;
  int e3 = (base + 3 < N) ? deg[base + 3] : 0;
  int t0 = e0, t1 = t0 + e1, t2 = t1 + e2, t3 = t2 + e3;
  lds[tid] = t3;
  __syncthreads();
  for (int off = 1; off < 256; off <<= 1) {
    int v = (tid >= off) ? lds[tid - off] : 0;
    __syncthreads();
    lds[tid] += v;
    __syncthreads();
  }
  int excl = (tid > 0) ? lds[tid - 1] : 0;
  if (base + 0 < N) incl[base + 0] = t0 + excl;
  if (base + 1 < N) incl[base + 1] = t1 + excl;
  if (base + 2 < N) incl[base + 2] = t2 + excl;
  if (base + 3 < N) incl[base + 3] = t3 + excl;
  if (tid == 255) sums[b] = lds[255];
}

__global__ void scan_top(const int* __restrict__ sums, int* __restrict__ offs, int nch) {
  if (threadIdx.x == 0 && blockIdx.x == 0) {
    int run = 0;
    for (int i = 0; i < nch; ++i) { offs[i] = run; run += sums[i]; }
  }
}

__global__ void finalize_rowptr(const int* __restrict__ incl, const int* __restrict__ offs,
                                int* __restrict__ rowptr, int N) {
  int n = blockIdx.x * blockDim.x + threadIdx.x;
  if (n < N) rowptr[n + 1] = incl[n] + offs[n / SCHUNK];
  if (n == 0) rowptr[0] = 0;
}

__global__ void fill_csr(const int* __restrict__ src, const int* __restrict__ dst,
                         const int* __restrict__ rowptr, int* __restrict__ fill,
                         int* __restrict__ csr_src, int E) {
  int e = blockIdx.x * blockDim.x + threadIdx.x;
  if (e < E) {
    int d = dst[e];
    int pos = rowptr[d] + atomicAdd(&fill[d], 1);
    csr_src[pos] = src[e];
  }
}

// ---------------- fused 4-way linear (fp32 accum) ----------------
// y=0: q (fp32), y=1: k (bf16 -> kv slot low 8B), y=2: v (bf16 -> kv slot high 8B),
// y=3: skip/out-init (fp32).

__device__ inline unsigned pack_bf16_2(float a, float b) {
  unsigned ua = __float_as_uint(a);
  unsigned ub = __float_as_uint(b);
  ua = (ua + 0x7fffu + ((ua >> 16) & 1u)) >> 16;
  ub = (ub + 0x7fffu + ((ub >> 16) & 1u)) >> 16;
  return ua | (ub << 16);
}

template <int DIN>
__global__ __launch_bounds__(256) void tiled_linear(
    const float* __restrict__ x, int N,
    const float* __restrict__ W0, const float* __restrict__ B0, float* __restrict__ Oq,
    const float* __restrict__ W1, const float* __restrict__ B1,
    const float* __restrict__ W2, const float* __restrict__ B2, unsigned* __restrict__ KV,
    const float* __restrict__ W3, const float* __restrict__ B3, float* __restrict__ Os) {
  constexpr int NT = 64;
  constexpr int LDX = NT + 4;
  __shared__ float xs[DIN * LDX];
  const float* W; const float* B;
  switch (blockIdx.y) {
    case 0: W = W0; B = B0; break;
    case 1: W = W1; B = B1; break;
    case 2: W = W2; B = B2; break;
    default: W = W3; B = B3; break;
  }
  int tid = threadIdx.x;
  int n0 = blockIdx.x * NT;
  for (int idx = tid; idx < DIN * NT; idx += 256) {
    int nl = idx / DIN;
    int i = idx - nl * DIN;
    int n = n0 + nl;
    xs[i * LDX + nl] = (n < N) ? x[(size_t)n * DIN + i] : 0.f;
  }
  __syncthreads();

  int tc = tid & 31;
  int tn = tid >> 5;
  float acc[8][4];
#pragma unroll
  for (int a = 0; a < 8; ++a)
#pragma unroll
    for (int c = 0; c < 4; ++c) acc[a][c] = 0.f;

  const float4* Wp = (const float4*)W + tc;
  for (int i = 0; i < DIN; ++i) {
    float4 w4 = Wp[(size_t)i * 32];
    float4 xa = *(const float4*)&xs[i * LDX + 8 * tn];
    float4 xb = *(const float4*)&xs[i * LDX + 8 * tn + 4];
    float xv[8] = {xa.x, xa.y, xa.z, xa.w, xb.x, xb.y, xb.z, xb.w};
#pragma unroll
    for (int a = 0; a < 8; ++a) {
      acc[a][0] += xv[a] * w4.x;
      acc[a][1] += xv[a] * w4.y;
      acc[a][2] += xv[a] * w4.z;
      acc[a][3] += xv[a] * w4.w;
    }
  }
  float4 b4 = *(const float4*)&B[4 * tc];
  int y = blockIdx.y;
  if (y == 1 || y == 2) {
    int vo = (y == 2) ? 2 : 0;  // uint offset inside 16B slot
#pragma unroll
    for (int a = 0; a < 8; ++a) {
      int n = n0 + 8 * tn + a;
      if (n < N) {
        uint2 w;
        w.x = pack_bf16_2(acc[a][0] + b4.x, acc[a][1] + b4.y);
        w.y = pack_bf16_2(acc[a][2] + b4.z, acc[a][3] + b4.w);
        *(uint2*)&KV[(size_t)n * 128 + tc * 4 + vo] = w;
      }
    }
  } else {
    float* O = (y == 0) ? Oq : Os;
#pragma unroll
    for (int a = 0; a < 8; ++a) {
      int n = n0 + 8 * tn + a;
      if (n < N) {
        float4 o;
        o.x = acc[a][0] + b4.x;
        o.y = acc[a][1] + b4.y;
        o.z = acc[a][2] + b4.z;
        o.w = acc[a][3] + b4.w;
        *(float4*)&O[(size_t)n * 128 + 4 * tc] = o;
      }
    }
  }
}

// ---------------- edge aggregation ----------------
// One wave per dst node; 2 x 32-lane groups, each an independent online-softmax
// stream over alternating edges; merged at the end. kv row = 32 x 16B slots,
// slot l = {k[4l..4l+3], v[4l..4l+3]} bf16.

template <bool RELU>
__global__ __launch_bounds__(256) void edge_agg2(
    const float4* __restrict__ q, const uint4* __restrict__ kv,
    const int* __restrict__ rowptr, const int* __restrict__ csr_src,
    float* __restrict__ out, int N) {
  int tid = threadIdx.x;
  int lane = tid & 63;
  int wv = tid >> 6;
  int n = blockIdx.x * 4 + wv;
  if (n >= N) return;
  int g = lane >> 5;
  int l = lane & 31;
  float4 q4 = q[(size_t)n * 32 + l];
  int beg = rowptr[n];
  int deg = rowptr[n + 1] - beg;
  float m = -INFINITY, lsum = 0.f;
  float a0 = 0.f, a1 = 0.f, a2 = 0.f, a3 = 0.f;
  const float scale = 0.08838834764831845f;  // 1/sqrt(128)
  int cnt = (deg - g + 1) >> 1;
  const int* cp = csr_src + beg + g;
  uint4 kv0 = {0, 0, 0, 0}, kv1 = {0, 0, 0, 0};
  if (cnt >= 1) kv0 = kv[(size_t)cp[0] * 32 + l];
  if (cnt >= 2) kv1 = kv[(size_t)cp[2] * 32 + l];
  for (int it = 0; it < cnt; ++it) {
    uint4 cur = kv0;
    kv0 = kv1;
    if (it + 2 < cnt) kv1 = kv[(size_t)cp[2 * (it + 2)] * 32 + l];
    float k0 = __uint_as_float(cur.x << 16);
    float k1 = __uint_as_float(cur.x & 0xffff0000u);
    float k2 = __uint_as_float(cur.y << 16);
    float k3 = __uint_as_float(cur.y & 0xffff0000u);
    float d = q4.x * k0 + q4.y * k1 + q4.z * k2 + q4.w * k3;
#pragma unroll
    for (int off = 1; off < 32; off <<= 1) d += __shfl_xor(d, off);
    float sc = d * scale;
    float mn = fmaxf(m, sc);
    float cf = __expf(m - mn);
    float ef = __expf(sc - mn);
    float v0 = __uint_as_float(cur.z << 16);
    float v1 = __uint_as_float(cur.z & 0xffff0000u);
    float v2 = __uint_as_float(cur.w << 16);
    float v3 = __uint_as_float(cur.w & 0xffff0000u);
    lsum = lsum * cf + ef;
    a0 = a0 * cf + ef * v0;
    a1 = a1 * cf + ef * v1;
    a2 = a2 * cf + ef * v2;
    a3 = a3 * cf + ef * v3;
    m = mn;
  }
  // merge the two streams (lane ^ 32)
  float m2 = __shfl_xor(m, 32);
  float L2 = __shfl_xor(lsum, 32);
  float b0 = __shfl_xor(a0, 32);
  float b1 = __shfl_xor(a1, 32);
  float b2 = __shfl_xor(a2, 32);
  float b3 = __shfl_xor(a3, 32);
  if (lane < 32) {
    float ox0 = 0.f, ox1 = 0.f, ox2 = 0.f, ox3 = 0.f;
    if (deg > 0) {
      float M = fmaxf(m, m2);
      float c1 = __expf(m - M);
      float c2 = __expf(m2 - M);
      float rl = 1.f / (lsum * c1 + L2 * c2 + 1e-16f);
      ox0 = (a0 * c1 + b0 * c2) * rl;
      ox1 = (a1 * c1 + b1 * c2) * rl;
      ox2 = (a2 * c1 + b2 * c2) * rl;
      ox3 = (a3 * c1 + b3 * c2) * rl;
    }
    float* op = out + (size_t)n * 128 + 4 * l;
    float4 o = *(const float4*)op;
    o.x += ox0; o.y += ox1; o.z += ox2; o.w += ox3;
    if (RELU) {
      o.x = fmaxf(o.x, 0.f);
      o.y = fmaxf(o.y, 0.f);
      o.z = fmaxf(o.z, 0.f);
      o.w = fmaxf(o.w, 0.f);
    }
    *(float4*)op = o;
  }
}

// ---------------- global mean pool (batch sorted) ----------------

__global__ __launch_bounds__(128) void pool_kernel(const float* __restrict__ h,
                                                   const int* __restrict__ batch,
                                                   float* __restrict__ out, int N) {
  int g = blockIdx.x;
  int lo = 0, hi = N;
  while (lo < hi) { int mid = (lo + hi) >> 1; if (batch[mid] < g) lo = mid + 1; else hi = mid; }
  int s0 = lo;
  hi = N;
  while (lo < hi) { int mid = (lo + hi) >> 1; if (batch[mid] <= g) lo = mid + 1; else hi = mid; }
  int s1 = lo;
  int j = threadIdx.x;
  float acc = 0.f;
  for (int n = s0; n < s1; ++n) acc += h[(size_t)n * 128 + j];
  out[(size_t)g * 128 + j] = acc / fmaxf((float)(s1 - s0), 1.f);
}

// ---------------- launch ----------------

extern "C" void kernel_launch(void* const* d_in, const int* in_sizes, int n_in,
                              void* d_out, int out_size, void* d_ws, size_t ws_size,
                              hipStream_t stream) {
  const float* x = (const float*)d_in[0];
  const int* ei = (const int*)d_in[1];
  const int* batch = (const int*)d_in[2];
  const float* Wq1 = (const float*)d_in[3];
  const float* bq1 = (const float*)d_in[4];
  const float* Wk1 = (const float*)d_in[5];
  const float* bk1 = (const float*)d_in[6];
  const float* Wv1 = (const float*)d_in[7];
  const float* bv1 = (const float*)d_in[8];
  const float* Ws1 = (const float*)d_in[9];
  const float* bs1 = (const float*)d_in[10];
  const float* Wq2 = (const float*)d_in[11];
  const float* bq2 = (const float*)d_in[12];
  const float* Wk2 = (const float*)d_in[13];
  const float* bk2 = (const float*)d_in[14];
  const float* Wv2 = (const float*)d_in[15];
  const float* bv2 = (const float*)d_in[16];
  const float* Ws2 = (const float*)d_in[17];
  const float* bs2 = (const float*)d_in[18];

  int N = in_sizes[0] / D1;  // 50000
  int E = in_sizes[1] / 2;   // 800000
  int NG = out_size / DH;    // 512
  const int* src = ei;
  const int* dst = ei + E;

  char* ws = (char*)d_ws;
  float* q = (float*)ws;     ws += (size_t)N * DH * 4;
  unsigned* kvb = (unsigned*)ws; ws += (size_t)N * DH * 4;  // bf16 k+v interleaved, 512B/node
  float* h1 = (float*)ws;    ws += (size_t)N * DH * 4;
  float* h2 = (float*)ws;    ws += (size_t)N * DH * 4;
  int* rowptr = (int*)ws;    ws += (size_t)(N + 1) * 4;
  ws += 252;  // align
  int* deg = (int*)ws;  ws += (size_t)N * 4;
  int* fill = (int*)ws; ws += (size_t)N * 4;
  int* incl = (int*)ws; ws += (size_t)N * 4;
  int* offs = (int*)ws; ws += 1024;
  int* sums = (int*)ws; ws += 1024;
  int* csr = (int*)ws;  ws += (size_t)E * 4;

  int nch = (N + SCHUNK - 1) / SCHUNK;

  hipMemsetAsync(deg, 0, (size_t)N * 4, stream);
  hipMemsetAsync(fill, 0, (size_t)N * 4, stream);

  hist_kernel<<<(E + 255) / 256, 256, 0, stream>>>(dst, deg, E);
  scan_chunks<<<nch, 256, 0, stream>>>(deg, incl, sums, N);
  scan_top<<<1, 64, 0, stream>>>(sums, offs, nch);
  finalize_rowptr<<<(N + 255) / 256, 256, 0, stream>>>(incl, offs, rowptr, N);
  fill_csr<<<(E + 255) / 256, 256, 0, stream>>>(src, dst, rowptr, fill, csr, E);

  dim3 gl((N + 63) / 64, 4);
  // layer 1
  tiled_linear<D1><<<gl, 256, 0, stream>>>(x, N, Wq1, bq1, q, Wk1, bk1,
                                           Wv1, bv1, kvb, Ws1, bs1, h1);
  edge_agg2<true><<<(N + 3) / 4, 256, 0, stream>>>(
      (const float4*)q, (const uint4*)kvb, rowptr, csr, h1, N);
  // layer 2
  tiled_linear<DH><<<gl, 256, 0, stream>>>(h1, N, Wq2, bq2, q, Wk2, bk2,
                                           Wv2, bv2, kvb, Ws2, bs2, h2);
  edge_agg2<false><<<(N + 3) / 4, 256, 0, stream>>>(
      (const float4*)q, (const uint4*)kvb, rowptr, csr, h2, N);
  // mean pool
  pool_kernel<<<NG, 128, 0, stream>>>(h2, batch, (float*)d_out, N);
}